// Round 19
// baseline (402.677 us; speedup 1.0000x reference)
//
#include <hip/hip_runtime.h>
#include <hip/hip_cooperative_groups.h>

namespace cg = cooperative_groups;

// KAN forward: 3 layers of [deg-3 B-spline basis (64 bases) -> einsum 'bik,ijk->bj'].
// Only 4 basis values are nonzero per point => 4-tap gather per (i,j).
//
// NUMERICS (frozen since R6 — absmax sits exactly at threshold; per-(b,j)
// product set and fp64 add order must stay bitwise-identical):
//  * knots: jnp.linspace fp32 semantics, endpoint forced to 1.0f
//  * basis: fp32 Cox-de Boor, reference expression tree, contraction OFF
//  * einsum: fp64 accumulation, per-(b,j) order = i ascending, k ascending
//  * skipping an i whose 4 weights are all +/-0 only removes exact +/-0.0
//    adds — IEEE-exact no-ops (validated R7-R18)
//
// PERF: R6 1967 -> R9 420 -> R14 371 -> R15 330 -> R16 213 -> R17 190 ->
// R18 185.7.  R18 falsifier fired: 16x fewer transpose instrs moved the
// ~70us gap by only 5us => gap is the INTER-DISPATCH machinery (kernel-
// boundary drain + L2 invalidate/writeback between graph nodes), not
// transpose execution.  R19: ONE cooperative kernel — phase A transposes
// (1536 tiles / 1024 blocks), __threadfence + grid.sync (provides the
// cross-XCD visibility the kernel boundary used to), phase B = mega3 body.
// LDS reused between phases (20.5KB -> 7 blocks/CU co-residency, 1792>=1024).

#define NBATCH 4096

typedef float f4a __attribute__((ext_vector_type(4), aligned(4)));

// jnp.linspace(0,1,68,f32): delta = fl32(1/67); K[m] = fl32(m)*delta; K[67]=1.
__device__ __forceinline__ float knotf(int m) {
    if (m == 67) return 1.0f;
    return (float)m * (1.0f / 67.0f);
}

// Bitwise replica of the reference Cox-de Boor recursion on the 7-wide
// nonzero window around span t.  w[r] = B_{t-3+r,3}(x), r=0..3.
__device__ __forceinline__ void basis4(float xf, int& t_out, float w[4]) {
#pragma clang fp contract(off)
    int t = (int)floorf(xf * 67.0f);
    t = t < 0 ? 0 : (t > 66 ? 66 : t);
    #pragma unroll
    for (int it = 0; it < 2; ++it) {   // enforce K[t] <= x < K[t+1] on fp32 knots
        if (t > 0 && xf < knotf(t)) --t;
        else if (t < 66 && xf >= knotf(t + 1)) ++t;
    }
    float W[7];
    #pragma unroll
    for (int j = 0; j < 7; ++j) W[j] = 0.0f;
    W[3] = 1.0f;   // degree-0 indicator at span t
    #pragma unroll
    for (int d = 1; d <= 3; ++d) {
        #pragma unroll
        for (int j = 0; j <= 6 - d; ++j) {
            const int k = t - 3 + j;
            const float ka = knotf(k);
            const float kb = knotf(k + d);
            const float kc = knotf(k + d + 1);
            const float ke = knotf(k + 1);
            const float lt = ((xf - ka) / (kb - ka)) * W[j];
            const float rt = ((kc - xf) / (kc - ke)) * W[j + 1];
            W[j] = lt + rt;
        }
    }
    t_out = t;
    w[0] = W[0]; w[1] = W[1]; w[2] = W[2]; w[3] = W[3];
}

// Shift-aligned table entry: k0 = clamp(t-3,0,60); w'[m] applies to C[k0+m],
// m-ascending == k-ascending == R6 order; displaced/OOB slots get w'=0.
__device__ __forceinline__ void make_wk(float xf, float4& wv, int& kv) {
    float wp[4] = {0.f, 0.f, 0.f, 0.f};
    int k0 = 0;
    if (xf >= 0.0f && xf < 1.0f) {
        int t; float w[4];
        basis4(xf, t, w);
        k0 = t - 3;
        k0 = k0 < 0 ? 0 : (k0 > 60 ? 60 : k0);
        const int s = (t - 3) - k0;
        #pragma unroll
        for (int m = 0; m < 4; ++m) {
            const int r = m - s;
            wp[m] = (r >= 0 && r <= 3) ? w[r] : 0.0f;
        }
    }
    wv = make_float4(wp[0], wp[1], wp[2], wp[3]);
    kv = k0;
}

// ---------------- wave compaction, IN-PLACE ---------------------------------
// Entry order e ascending (= i ascending) preserved.  Write pos <= read index
// per pass; wave reads all 64 entries of a pass (lockstep) before writing ->
// race-free.  -0.0 counts as zero; dropped entries are exact no-op adds.
__device__ __forceinline__ int compact_wave(int lane, int passes,
        float4* __restrict__ wbuf, int* __restrict__ kbuf, int mult) {
    int base = 0;
    for (int p = 0; p < passes; ++p) {
        const int e = 64 * p + lane;
        const float4 wv = wbuf[e];
        const int    kv = kbuf[e];
        const bool act = (wv.x != 0.f) || (wv.y != 0.f) ||
                         (wv.z != 0.f) || (wv.w != 0.f);
        const unsigned long long mask = __ballot(act);
        const int pos = base + (int)__popcll(mask & ((1ull << lane) - 1ull));
        if (act) { wbuf[pos] = wv; kbuf[pos] = (e * 64 + kv) * mult; }
        base += (int)__popcll(mask);
    }
    return base;   // wave-uniform
}

// ---------------- gather over an active list (OUT=256 layers) ---------------
// Wave = one b; lane owns j-quad.  Per entry: wave-uniform row offset
// (readfirstlane -> SGPR addressing), 4x 1KB b128 row loads, 16 f64 FMA
// (entry-asc = i-asc, k-asc == R6 order), dist-2 prefetch (8 f4a in flight).
__device__ __forceinline__ void gather_list(const float* __restrict__ Ct,
        const float4* __restrict__ wl, const int* __restrict__ rl,
        int cnt, int j0, double acc[4]) {
    if (cnt <= 0) return;
    f4a c0[4], c1[4];
    {
        const int r0 = __builtin_amdgcn_readfirstlane(rl[0]);
        const float* p = Ct + r0 + j0;
        c0[0] = *(const f4a*)(p);       c0[1] = *(const f4a*)(p + 256);
        c0[2] = *(const f4a*)(p + 512); c0[3] = *(const f4a*)(p + 768);
    }
    {
        const int e1 = (cnt > 1) ? 1 : 0;
        const int r1 = __builtin_amdgcn_readfirstlane(rl[e1]);
        const float* p = Ct + r1 + j0;
        c1[0] = *(const f4a*)(p);       c1[1] = *(const f4a*)(p + 256);
        c1[2] = *(const f4a*)(p + 512); c1[3] = *(const f4a*)(p + 768);
    }
    for (int e = 0; e < cnt; ++e) {
        const int ep = (e + 2 < cnt) ? e + 2 : cnt - 1;
        const int rN = __builtin_amdgcn_readfirstlane(rl[ep]);
        f4a c2[4];
        {
            const float* p = Ct + rN + j0;
            c2[0] = *(const f4a*)(p);       c2[1] = *(const f4a*)(p + 256);
            c2[2] = *(const f4a*)(p + 512); c2[3] = *(const f4a*)(p + 768);
        }
        const float4 wv = wl[e];
        const double w0 = (double)wv.x, w1 = (double)wv.y;
        const double w2 = (double)wv.z, w3 = (double)wv.w;
        #pragma unroll
        for (int ee = 0; ee < 4; ++ee) {
            acc[ee] = fma(w0, (double)c0[0][ee], acc[ee]);   // k-ascending == R6
            acc[ee] = fma(w1, (double)c0[1][ee], acc[ee]);
            acc[ee] = fma(w2, (double)c0[2][ee], acc[ee]);
            acc[ee] = fma(w3, (double)c0[3][ee], acc[ee]);
        }
        #pragma unroll
        for (int r = 0; r < 4; ++r) { c0[r] = c1[r]; c1[r] = c2[r]; }
    }
}

// ---------------- cooperative all-in-one kernel -----------------------------
__global__ __launch_bounds__(256) void kan_all(
        const float* __restrict__ x,       // [4096][64]
        const float* __restrict__ C0, const float* __restrict__ C1,
        const float* __restrict__ C2,
        float* __restrict__ Ct0,           // [64][64][256]
        float* __restrict__ Ct1,           // [256][64][256]
        float* __restrict__ Ct2,           // [256][64][64]
        float* __restrict__ out) {         // [4096][64]
    __shared__ __align__(16) char shmem[20512];

    const int bid = blockIdx.x, tid = threadIdx.x;

    // ======== phase A: transpose C[i][j][k] -> Ct[i][k][j], 1536 tiles ======
    {
        float (*t)[65] = reinterpret_cast<float (*)[65]>(shmem);  // 64x65 tile
        for (int u = bid; u < 1536; u += 1024) {
            const float* C; float* Ct; int OUT, i, jt;
            if (u < 256)       { C = C0; Ct = Ct0; OUT = 256; i = u >> 2;         jt = u & 3; }
            else if (u < 1280) { C = C1; Ct = Ct1; OUT = 256; i = (u - 256) >> 2; jt = (u - 256) & 3; }
            else               { C = C2; Ct = Ct2; OUT = 64;  i = u - 1280;       jt = 0; }
            const int j0t = jt * 64;
            const float* src = C + ((size_t)i * OUT + j0t) * 64;
            float* dst = Ct + (size_t)i * 64 * OUT + j0t;

            const int kq  = tid & 15;
            const int jl0 = tid >> 4;
            #pragma unroll
            for (int p = 0; p < 4; ++p) {
                const int jl = jl0 + 16 * p;
                const f4a v = *(const f4a*)(src + (size_t)jl * 64 + kq * 4);
                t[kq * 4 + 0][jl] = v[0];
                t[kq * 4 + 1][jl] = v[1];
                t[kq * 4 + 2][jl] = v[2];
                t[kq * 4 + 3][jl] = v[3];
            }
            __syncthreads();
            const int jq  = tid & 15;
            const int kl0 = tid >> 4;
            #pragma unroll
            for (int p = 0; p < 4; ++p) {
                const int k = kl0 + 16 * p;
                f4a o;
                o[0] = t[k][jq * 4 + 0];
                o[1] = t[k][jq * 4 + 1];
                o[2] = t[k][jq * 4 + 2];
                o[3] = t[k][jq * 4 + 3];
                *(f4a*)(dst + (size_t)k * OUT + jq * 4) = o;
            }
            __syncthreads();   // protect tile reuse for second unit
        }
    }
    __threadfence();                 // release phase-A writes device-wide
    cg::this_grid().sync();          // all Ct complete & visible

    // ======== phase B: mega3 body (tables reuse shmem) ======================
    float4* wtab = reinterpret_cast<float4*>(shmem);                 // [4][256]
    int*    ktab = reinterpret_cast<int*>(shmem + 16384);            // [4][256]
    int*    scnt = reinterpret_cast<int*>(shmem + 16384 + 4096);     // [4]

    const int lane = tid & 63;
    const int wx   = tid >> 6;
    const int b    = bid * 4 + wx;
    const int j0   = lane * 4;
    float4* wt = wtab + wx * 256;
    int*    kt = ktab + wx * 256;

    // ---- L1 table from x: 64 entries, all kept (x uniform in [0,1)) ----
    {
        float4 wv; int kv;
        make_wk(x[(size_t)b * 64 + lane], wv, kv);
        wt[lane] = wv;
        kt[lane] = (lane * 64 + kv) * 256;   // row offset directly
    }
    double acc1[4] = {0.0, 0.0, 0.0, 0.0};
    gather_list(Ct0, wt, kt, 64, j0, acc1);

    // ---- a1 rounding -> raw table -> in-place compacted L2 list ----
    #pragma unroll
    for (int e = 0; e < 4; ++e) {
        float4 wv; int kv;
        make_wk((float)acc1[e], wv, kv);   // same fp32 value as R18
        wt[j0 + e] = wv;
        kt[j0 + e] = kv;
    }
    const int cnt2 = compact_wave(lane, 4, wt, kt, 256);

    double acc2[4] = {0.0, 0.0, 0.0, 0.0};
    gather_list(Ct1, wt, kt, cnt2, j0, acc2);

    // ---- a2 rounding -> raw table -> in-place compacted L3 list ----
    #pragma unroll
    for (int e = 0; e < 4; ++e) {
        float4 wv; int kv;
        make_wk((float)acc2[e], wv, kv);
        wt[j0 + e] = wv;
        kt[j0 + e] = kv;
    }
    const int cnt3 = compact_wave(lane, 4, wt, kt, 64);
    if (lane == 0) scnt[wx] = cnt3;
    __syncthreads();
    if (wx != 0) return;

    // ---- layer 3 on wave 0: lane = (bsub, jq); 4-segment 1KB loads ----
    const int bsub = lane >> 4;
    const int jq   = lane & 15;
    const int cn   = scnt[bsub];
    const int cmax = max(max(scnt[0], scnt[1]), max(scnt[2], scnt[3]));
    double a3[4] = {0.0, 0.0, 0.0, 0.0};

    if (cmax > 0) {
        auto ldb = [&](int e, f4a p[4], float4& wv) {
            const int ec = (cn > 0) ? ((e < cn) ? e : cn - 1) : 0;
            wv = (cn > 0) ? wtab[bsub * 256 + ec] : make_float4(0.f, 0.f, 0.f, 0.f);
            int ro = (cn > 0) ? ktab[bsub * 256 + ec] : 0;
            if (e >= cn) wv = make_float4(0.f, 0.f, 0.f, 0.f);  // pad: exact no-op
            const float* pb = Ct2 + ro + jq * 4;
            p[0] = *(const f4a*)(pb);
            p[1] = *(const f4a*)(pb + 64);
            p[2] = *(const f4a*)(pb + 128);
            p[3] = *(const f4a*)(pb + 192);
        };
        f4a P0[4], P1[4]; float4 W0, W1;
        ldb(0, P0, W0);
        ldb(1, P1, W1);
        for (int e = 0; e < cmax; ++e) {
            f4a P2[4]; float4 W2;
            ldb(e + 2, P2, W2);
            const double w0 = (double)W0.x, w1 = (double)W0.y;
            const double w2 = (double)W0.z, w3 = (double)W0.w;
            #pragma unroll
            for (int ee = 0; ee < 4; ++ee) {
                a3[ee] = fma(w0, (double)P0[0][ee], a3[ee]);   // k-asc == R6
                a3[ee] = fma(w1, (double)P0[1][ee], a3[ee]);
                a3[ee] = fma(w2, (double)P0[2][ee], a3[ee]);
                a3[ee] = fma(w3, (double)P0[3][ee], a3[ee]);
            }
            #pragma unroll
            for (int r = 0; r < 4; ++r) { P0[r] = P1[r]; P1[r] = P2[r]; }
            W0 = W1; W1 = W2;
        }
    }

    const float4 o = make_float4((float)a3[0], (float)a3[1],
                                 (float)a3[2], (float)a3[3]);
    *(float4*)(out + (size_t)(bid * 4 + bsub) * 64 + jq * 4) = o;
}

// ---------------- two-kernel fallback (R18 proven) --------------------------

__global__ __launch_bounds__(256) void transpose_fast(
        const float* __restrict__ C0, const float* __restrict__ C1,
        const float* __restrict__ C2, float* __restrict__ Ct0,
        float* __restrict__ Ct1, float* __restrict__ Ct2) {
    __shared__ float t[64][65];
    const int bid = blockIdx.x, tid = threadIdx.x;
    const float* C; float* Ct; int OUT, i, jt;
    if (bid < 256)       { C = C0; Ct = Ct0; OUT = 256; i = bid >> 2;          jt = bid & 3; }
    else if (bid < 1280) { C = C1; Ct = Ct1; OUT = 256; i = (bid - 256) >> 2;  jt = (bid - 256) & 3; }
    else                 { C = C2; Ct = Ct2; OUT = 64;  i = bid - 1280;        jt = 0; }
    const int j0 = jt * 64;
    const float* src = C + ((size_t)i * OUT + j0) * 64;
    float* dst = Ct + (size_t)i * 64 * OUT + j0;

    const int kq  = tid & 15;
    const int jl0 = tid >> 4;
    #pragma unroll
    for (int p = 0; p < 4; ++p) {
        const int jl = jl0 + 16 * p;
        const f4a v = *(const f4a*)(src + (size_t)jl * 64 + kq * 4);
        t[kq * 4 + 0][jl] = v[0];
        t[kq * 4 + 1][jl] = v[1];
        t[kq * 4 + 2][jl] = v[2];
        t[kq * 4 + 3][jl] = v[3];
    }
    __syncthreads();
    const int jq  = tid & 15;
    const int kl0 = tid >> 4;
    #pragma unroll
    for (int p = 0; p < 4; ++p) {
        const int k = kl0 + 16 * p;
        f4a o;
        o[0] = t[k][jq * 4 + 0];
        o[1] = t[k][jq * 4 + 1];
        o[2] = t[k][jq * 4 + 2];
        o[3] = t[k][jq * 4 + 3];
        *(f4a*)(dst + (size_t)k * OUT + jq * 4) = o;
    }
}

__global__ __launch_bounds__(256) void kan_mega3(
        const float* __restrict__ x, const float* __restrict__ Ct0,
        const float* __restrict__ Ct1, const float* __restrict__ Ct2,
        float* __restrict__ out) {
    __shared__ __align__(16) float4 wtab[4][256];
    __shared__ int                  ktab[4][256];
    __shared__ int scnt[4];

    const int tid  = threadIdx.x;
    const int lane = tid & 63;
    const int wx   = tid >> 6;
    const int b    = blockIdx.x * 4 + wx;
    const int j0   = lane * 4;

    {
        float4 wv; int kv;
        make_wk(x[(size_t)b * 64 + lane], wv, kv);
        wtab[wx][lane] = wv;
        ktab[wx][lane] = (lane * 64 + kv) * 256;
    }
    double acc1[4] = {0.0, 0.0, 0.0, 0.0};
    gather_list(Ct0, &wtab[wx][0], &ktab[wx][0], 64, j0, acc1);

    #pragma unroll
    for (int e = 0; e < 4; ++e) {
        float4 wv; int kv;
        make_wk((float)acc1[e], wv, kv);
        wtab[wx][j0 + e] = wv;
        ktab[wx][j0 + e] = kv;
    }
    const int cnt2 = compact_wave(lane, 4, &wtab[wx][0], &ktab[wx][0], 256);

    double acc2[4] = {0.0, 0.0, 0.0, 0.0};
    gather_list(Ct1, &wtab[wx][0], &ktab[wx][0], cnt2, j0, acc2);

    #pragma unroll
    for (int e = 0; e < 4; ++e) {
        float4 wv; int kv;
        make_wk((float)acc2[e], wv, kv);
        wtab[wx][j0 + e] = wv;
        ktab[wx][j0 + e] = kv;
    }
    const int cnt3 = compact_wave(lane, 4, &wtab[wx][0], &ktab[wx][0], 64);
    if (lane == 0) scnt[wx] = cnt3;
    __syncthreads();
    if (wx != 0) return;

    const int bsub = lane >> 4;
    const int jq   = lane & 15;
    const int cn   = scnt[bsub];
    const int cmax = max(max(scnt[0], scnt[1]), max(scnt[2], scnt[3]));
    double a3[4] = {0.0, 0.0, 0.0, 0.0};

    if (cmax > 0) {
        auto ldb = [&](int e, f4a p[4], float4& wv) {
            const int ec = (cn > 0) ? ((e < cn) ? e : cn - 1) : 0;
            wv = (cn > 0) ? wtab[bsub][ec] : make_float4(0.f, 0.f, 0.f, 0.f);
            int ro = (cn > 0) ? ktab[bsub][ec] : 0;
            if (e >= cn) wv = make_float4(0.f, 0.f, 0.f, 0.f);
            const float* pb = Ct2 + ro + jq * 4;
            p[0] = *(const f4a*)(pb);
            p[1] = *(const f4a*)(pb + 64);
            p[2] = *(const f4a*)(pb + 128);
            p[3] = *(const f4a*)(pb + 192);
        };
        f4a P0[4], P1[4]; float4 W0, W1;
        ldb(0, P0, W0);
        ldb(1, P1, W1);
        for (int e = 0; e < cmax; ++e) {
            f4a P2[4]; float4 W2;
            ldb(e + 2, P2, W2);
            const double w0 = (double)W0.x, w1 = (double)W0.y;
            const double w2 = (double)W0.z, w3 = (double)W0.w;
            #pragma unroll
            for (int ee = 0; ee < 4; ++ee) {
                a3[ee] = fma(w0, (double)P0[0][ee], a3[ee]);
                a3[ee] = fma(w1, (double)P0[1][ee], a3[ee]);
                a3[ee] = fma(w2, (double)P0[2][ee], a3[ee]);
                a3[ee] = fma(w3, (double)P0[3][ee], a3[ee]);
            }
            #pragma unroll
            for (int r = 0; r < 4; ++r) { P0[r] = P1[r]; P1[r] = P2[r]; }
            W0 = W1; W1 = W2;
        }
    }

    const float4 o = make_float4((float)a3[0], (float)a3[1],
                                 (float)a3[2], (float)a3[3]);
    *(float4*)(out + (size_t)(blockIdx.x * 4 + bsub) * 64 + jq * 4) = o;
}

// ---------------- tier C: R6 monolithic (zero workspace, proven) ------------

__device__ __forceinline__ void stage1(float xf, float sw[4], int& st) {
    const bool inr = (xf >= 0.0f) && (xf < 1.0f);
    if (!inr) { st = -1; sw[0] = sw[1] = sw[2] = sw[3] = 0.0f; return; }
    int t; float w[4];
    basis4(xf, t, w);
    sw[0] = w[0]; sw[1] = w[1]; sw[2] = w[2]; sw[3] = w[3];
    st = t;
}

template<int IN, int OUT>
__device__ __forceinline__ float gather_acc(const float* __restrict__ C, int j,
                                            const float (*__restrict__ sw)[4],
                                            const int* __restrict__ st) {
    double acc = 0.0;
    for (int i = 0; i < IN; ++i) {
        const int t = st[i];
        if (t < 0) continue;
        const float* Crow = C + ((size_t)i * OUT + j) * 64;
        #pragma unroll
        for (int r = 0; r < 4; ++r) {
            const int k4 = t - 3 + r;
            if (k4 >= 0 && k4 <= 63)
                acc += (double)sw[i][r] * (double)Crow[k4];
        }
    }
    return (float)acc;
}

__global__ __launch_bounds__(256) void kan_fused(const float* __restrict__ x,
                                                 const float* __restrict__ C0,
                                                 const float* __restrict__ C1,
                                                 const float* __restrict__ C2,
                                                 float* __restrict__ out) {
    __shared__ float cur[256];
    __shared__ float sw[256][4];
    __shared__ int   st[256];
    const int b = blockIdx.x, tid = threadIdx.x;

    if (tid < 64) stage1(x[(size_t)b * 64 + tid], sw[tid], st[tid]);
    __syncthreads();
    {
        const float a = gather_acc<64, 256>(C0, tid, sw, st);
        __syncthreads();
        cur[tid] = a;
    }
    __syncthreads();

    stage1(cur[tid], sw[tid], st[tid]);
    __syncthreads();
    {
        const float a = gather_acc<256, 256>(C1, tid, sw, st);
        __syncthreads();
        cur[tid] = a;
    }
    __syncthreads();

    stage1(cur[tid], sw[tid], st[tid]);
    __syncthreads();
    if (tid < 64) out[(size_t)b * 64 + tid] = gather_acc<256, 64>(C2, tid, sw, st);
}

// ---------------- launcher --------------------------------------------------

extern "C" void kernel_launch(void* const* d_in, const int* in_sizes, int n_in,
                              void* d_out, int out_size, void* d_ws, size_t ws_size,
                              hipStream_t stream) {
    const float* x  = (const float*)d_in[0];   // (4096, 64)
    const float* C0 = (const float*)d_in[1];   // (64, 256, 64)
    const float* C1 = (const float*)d_in[2];   // (256, 256, 64)
    const float* C2 = (const float*)d_in[3];   // (256, 64, 64)
    float* out = (float*)d_out;                // (4096, 64)

    const size_t CT1 = (size_t)256 * 64 * 256 * 4;   // 16.78 MB
    const size_t CT0 = (size_t)64  * 64 * 256 * 4;   //  4.19 MB
    const size_t CT2 = (size_t)256 * 64 * 64  * 4;   //  4.19 MB
    const size_t need = CT1 + CT0 + CT2;             // 25.17 MB (R14-R18 proven)

    if (ws_size >= need) {
        float* ct1 = (float*)d_ws;
        float* ct0 = (float*)((char*)d_ws + CT1);
        float* ct2 = (float*)((char*)d_ws + CT1 + CT0);

        void* args[] = {(void*)&x, (void*)&C0, (void*)&C1, (void*)&C2,
                        (void*)&ct0, (void*)&ct1, (void*)&ct2, (void*)&out};
        hipError_t err = hipLaunchCooperativeKernel(
            (const void*)kan_all, dim3(1024), dim3(256), args, 0, stream);
        if (err != hipSuccess) {
            // proven R18 two-kernel path
            transpose_fast<<<1536, 256, 0, stream>>>(C0, C1, C2, ct0, ct1, ct2);
            kan_mega3<<<1024, 256, 0, stream>>>(x, ct0, ct1, ct2, out);
        }
    } else {
        kan_fused<<<NBATCH, 256, 0, stream>>>(x, C0, C1, C2, out);
    }
}

// Round 20
// 184.972 us; speedup vs baseline: 2.1770x; 2.1770x over previous
//
#include <hip/hip_runtime.h>

// KAN forward: 3 layers of [deg-3 B-spline basis (64 bases) -> einsum 'bik,ijk->bj'].
// Only 4 basis values are nonzero per point => 4-tap gather per (i,j).
//
// NUMERICS (frozen since R6 — absmax sits exactly at the 0.375 threshold with
// ZERO margin; per-(b,j) product set and fp64 add order must stay bitwise-
// identical; even fp64 reorder is forbidden):
//  * knots: jnp.linspace fp32 semantics, endpoint forced to 1.0f
//  * basis: fp32 Cox-de Boor, reference expression tree, contraction OFF
//  * einsum: fp64 accumulation, per-(b,j) order = i ascending, k ascending
//  * skipping an i whose 4 weights are all +/-0 only removes exact +/-0.0
//    adds — IEEE-exact no-ops (validated R7-R18)
//
// PERF trajectory: R6 1967 -> R7 711 -> R9 420 -> R14 371 -> R15 330 ->
// R16 213 (ballot-compacted sparsity: only ~7%/13% of L2/L3 inputs are
// in-domain) -> R17 190 (in-place compaction, 21KB LDS) -> R18 185.7
// (vectorized transpose) -> R19 403 REGRESSION (cooperative grid.sync on 8
// non-coherent XCDs costs ~200us; VALUBusy 55->19%).  R20: revert to R18.
//
// PLATEAU ANALYSIS (why this is the practical floor):
//  * mega3 117us = VMEM-issue 67us (1.5M wave-loads x ~27cyc/CU measured
//    issue cost; L1's 1.05M are compulsory — every (b,i,k0-row) is needed
//    once) ~50% overlapped with VALU 64us (frozen fp64 FMA/cvt + basis divs).
//  * Deeper overlap needs more waves/CU: j-split halves bytes/load (R12
//    regression), i-split reorders the fp64 chain (forbidden at zero margin).
//  * ~55us is fixed harness/graph overhead: 4->2 dispatches moved it ~6us
//    (R16->R17); 16x fewer transpose instrs moved it 5us (R18); fusing the
//    boundary away cost +215us (R19).  All three falsifiers fired.

#define NBATCH 4096

typedef float f4a __attribute__((ext_vector_type(4), aligned(4)));

// jnp.linspace(0,1,68,f32): delta = fl32(1/67); K[m] = fl32(m)*delta; K[67]=1.
__device__ __forceinline__ float knotf(int m) {
    if (m == 67) return 1.0f;
    return (float)m * (1.0f / 67.0f);
}

// Bitwise replica of the reference Cox-de Boor recursion on the 7-wide
// nonzero window around span t.  w[r] = B_{t-3+r,3}(x), r=0..3.
__device__ __forceinline__ void basis4(float xf, int& t_out, float w[4]) {
#pragma clang fp contract(off)
    int t = (int)floorf(xf * 67.0f);
    t = t < 0 ? 0 : (t > 66 ? 66 : t);
    #pragma unroll
    for (int it = 0; it < 2; ++it) {   // enforce K[t] <= x < K[t+1] on fp32 knots
        if (t > 0 && xf < knotf(t)) --t;
        else if (t < 66 && xf >= knotf(t + 1)) ++t;
    }
    float W[7];
    #pragma unroll
    for (int j = 0; j < 7; ++j) W[j] = 0.0f;
    W[3] = 1.0f;   // degree-0 indicator at span t
    #pragma unroll
    for (int d = 1; d <= 3; ++d) {
        #pragma unroll
        for (int j = 0; j <= 6 - d; ++j) {
            const int k = t - 3 + j;
            const float ka = knotf(k);
            const float kb = knotf(k + d);
            const float kc = knotf(k + d + 1);
            const float ke = knotf(k + 1);
            const float lt = ((xf - ka) / (kb - ka)) * W[j];
            const float rt = ((kc - xf) / (kc - ke)) * W[j + 1];
            W[j] = lt + rt;
        }
    }
    t_out = t;
    w[0] = W[0]; w[1] = W[1]; w[2] = W[2]; w[3] = W[3];
}

// Shift-aligned table entry: k0 = clamp(t-3,0,60); w'[m] applies to C[k0+m],
// m-ascending == k-ascending == R6 order; displaced/OOB slots get w'=0.
__device__ __forceinline__ void make_wk(float xf, float4& wv, int& kv) {
    float wp[4] = {0.f, 0.f, 0.f, 0.f};
    int k0 = 0;
    if (xf >= 0.0f && xf < 1.0f) {
        int t; float w[4];
        basis4(xf, t, w);
        k0 = t - 3;
        k0 = k0 < 0 ? 0 : (k0 > 60 ? 60 : k0);
        const int s = (t - 3) - k0;
        #pragma unroll
        for (int m = 0; m < 4; ++m) {
            const int r = m - s;
            wp[m] = (r >= 0 && r <= 3) ? w[r] : 0.0f;
        }
    }
    wv = make_float4(wp[0], wp[1], wp[2], wp[3]);
    kv = k0;
}

// ---------------- fast fused transpose: C[i][j][k] -> Ct[i][k][j] -----------
// 64j x 64k tile per block, float4 both sides (1KB/wave-instr in 4x256B
// segments), 64x65 LDS (2-way banks both phases, free per m136).
__global__ __launch_bounds__(256) void transpose_fast(
        const float* __restrict__ C0, const float* __restrict__ C1,
        const float* __restrict__ C2, float* __restrict__ Ct0,
        float* __restrict__ Ct1, float* __restrict__ Ct2) {
    __shared__ float t[64][65];
    const int bid = blockIdx.x, tid = threadIdx.x;
    const float* C; float* Ct; int OUT, i, jt;
    if (bid < 256)       { C = C0; Ct = Ct0; OUT = 256; i = bid >> 2;          jt = bid & 3; }
    else if (bid < 1280) { C = C1; Ct = Ct1; OUT = 256; i = (bid - 256) >> 2;  jt = (bid - 256) & 3; }
    else                 { C = C2; Ct = Ct2; OUT = 64;  i = bid - 1280;        jt = 0; }
    const int j0 = jt * 64;
    const float* src = C + ((size_t)i * OUT + j0) * 64;
    float* dst = Ct + (size_t)i * 64 * OUT + j0;

    const int kq  = tid & 15;
    const int jl0 = tid >> 4;
    #pragma unroll
    for (int p = 0; p < 4; ++p) {
        const int jl = jl0 + 16 * p;
        const f4a v = *(const f4a*)(src + (size_t)jl * 64 + kq * 4);
        t[kq * 4 + 0][jl] = v[0];
        t[kq * 4 + 1][jl] = v[1];
        t[kq * 4 + 2][jl] = v[2];
        t[kq * 4 + 3][jl] = v[3];
    }
    __syncthreads();
    const int jq  = tid & 15;
    const int kl0 = tid >> 4;
    #pragma unroll
    for (int p = 0; p < 4; ++p) {
        const int k = kl0 + 16 * p;
        f4a o;
        o[0] = t[k][jq * 4 + 0];
        o[1] = t[k][jq * 4 + 1];
        o[2] = t[k][jq * 4 + 2];
        o[3] = t[k][jq * 4 + 3];
        *(f4a*)(dst + (size_t)k * OUT + jq * 4) = o;
    }
}

// ---------------- wave compaction, IN-PLACE ---------------------------------
// Entry order e ascending (= i ascending) preserved.  Write pos <= read index
// per pass; wave reads all 64 entries of a pass (lockstep) before writing ->
// race-free.  -0.0 counts as zero; dropped entries are exact no-op adds.
__device__ __forceinline__ int compact_wave(int lane, int passes,
        float4* __restrict__ wbuf, int* __restrict__ kbuf, int mult) {
    int base = 0;
    for (int p = 0; p < passes; ++p) {
        const int e = 64 * p + lane;
        const float4 wv = wbuf[e];
        const int    kv = kbuf[e];
        const bool act = (wv.x != 0.f) || (wv.y != 0.f) ||
                         (wv.z != 0.f) || (wv.w != 0.f);
        const unsigned long long mask = __ballot(act);
        const int pos = base + (int)__popcll(mask & ((1ull << lane) - 1ull));
        if (act) { wbuf[pos] = wv; kbuf[pos] = (e * 64 + kv) * mult; }
        base += (int)__popcll(mask);
    }
    return base;   // wave-uniform
}

// ---------------- gather over an active list (OUT=256 layers) ---------------
// Wave = one b; lane owns j-quad.  Per entry: wave-uniform row offset
// (readfirstlane -> SGPR addressing), 4x 1KB b128 row loads, 16 f64 FMA
// (entry-asc = i-asc, k-asc == R6 order), dist-2 prefetch (8 f4a in flight).
__device__ __forceinline__ void gather_list(const float* __restrict__ Ct,
        const float4* __restrict__ wl, const int* __restrict__ rl,
        int cnt, int j0, double acc[4]) {
    if (cnt <= 0) return;
    f4a c0[4], c1[4];
    {
        const int r0 = __builtin_amdgcn_readfirstlane(rl[0]);
        const float* p = Ct + r0 + j0;
        c0[0] = *(const f4a*)(p);       c0[1] = *(const f4a*)(p + 256);
        c0[2] = *(const f4a*)(p + 512); c0[3] = *(const f4a*)(p + 768);
    }
    {
        const int e1 = (cnt > 1) ? 1 : 0;
        const int r1 = __builtin_amdgcn_readfirstlane(rl[e1]);
        const float* p = Ct + r1 + j0;
        c1[0] = *(const f4a*)(p);       c1[1] = *(const f4a*)(p + 256);
        c1[2] = *(const f4a*)(p + 512); c1[3] = *(const f4a*)(p + 768);
    }
    for (int e = 0; e < cnt; ++e) {
        const int ep = (e + 2 < cnt) ? e + 2 : cnt - 1;
        const int rN = __builtin_amdgcn_readfirstlane(rl[ep]);
        f4a c2[4];
        {
            const float* p = Ct + rN + j0;
            c2[0] = *(const f4a*)(p);       c2[1] = *(const f4a*)(p + 256);
            c2[2] = *(const f4a*)(p + 512); c2[3] = *(const f4a*)(p + 768);
        }
        const float4 wv = wl[e];
        const double w0 = (double)wv.x, w1 = (double)wv.y;
        const double w2 = (double)wv.z, w3 = (double)wv.w;
        #pragma unroll
        for (int ee = 0; ee < 4; ++ee) {
            acc[ee] = fma(w0, (double)c0[0][ee], acc[ee]);   // k-ascending == R6
            acc[ee] = fma(w1, (double)c0[1][ee], acc[ee]);
            acc[ee] = fma(w2, (double)c0[2][ee], acc[ee]);
            acc[ee] = fma(w3, (double)c0[3][ee], acc[ee]);
        }
        #pragma unroll
        for (int r = 0; r < 4; ++r) { c0[r] = c1[r]; c1[r] = c2[r]; }
    }
}

// ---------------- mega kernel: all 3 layers, compacted L2/L3 ----------------
__global__ __launch_bounds__(256) void kan_mega3(
        const float* __restrict__ x,       // [4096][64]
        const float* __restrict__ Ct0,     // [64][64][256]
        const float* __restrict__ Ct1,     // [256][64][256]
        const float* __restrict__ Ct2,     // [256][64][64]
        float* __restrict__ out) {         // [4096][64]
    __shared__ __align__(16) float4 wtab[4][256];
    __shared__ int                  ktab[4][256];
    __shared__ int scnt[4];

    const int tid  = threadIdx.x;
    const int lane = tid & 63;
    const int wx   = tid >> 6;
    const int b    = blockIdx.x * 4 + wx;
    const int j0   = lane * 4;

    // ---- L1 table from x: 64 entries, all kept (x uniform in [0,1)) ----
    {
        float4 wv; int kv;
        make_wk(x[(size_t)b * 64 + lane], wv, kv);
        wtab[wx][lane] = wv;
        ktab[wx][lane] = (lane * 64 + kv) * 256;   // row offset directly
    }
    double acc1[4] = {0.0, 0.0, 0.0, 0.0};
    gather_list(Ct0, &wtab[wx][0], &ktab[wx][0], 64, j0, acc1);

    // ---- a1 rounding -> raw table -> in-place compacted L2 list ----
    #pragma unroll
    for (int e = 0; e < 4; ++e) {
        float4 wv; int kv;
        make_wk((float)acc1[e], wv, kv);   // same fp32 value as R18
        wtab[wx][j0 + e] = wv;
        ktab[wx][j0 + e] = kv;
    }
    const int cnt2 = compact_wave(lane, 4, &wtab[wx][0], &ktab[wx][0], 256);

    double acc2[4] = {0.0, 0.0, 0.0, 0.0};
    gather_list(Ct1, &wtab[wx][0], &ktab[wx][0], cnt2, j0, acc2);

    // ---- a2 rounding -> raw table -> in-place compacted L3 list ----
    #pragma unroll
    for (int e = 0; e < 4; ++e) {
        float4 wv; int kv;
        make_wk((float)acc2[e], wv, kv);
        wtab[wx][j0 + e] = wv;
        ktab[wx][j0 + e] = kv;
    }
    const int cnt3 = compact_wave(lane, 4, &wtab[wx][0], &ktab[wx][0], 64);
    if (lane == 0) scnt[wx] = cnt3;
    __syncthreads();
    if (wx != 0) return;

    // ---- layer 3 on wave 0: lane = (bsub, jq); 4-segment 1KB loads ----
    const int bsub = lane >> 4;
    const int jq   = lane & 15;
    const int cn   = scnt[bsub];
    const int cmax = max(max(scnt[0], scnt[1]), max(scnt[2], scnt[3]));
    double a3[4] = {0.0, 0.0, 0.0, 0.0};

    if (cmax > 0) {
        auto ldb = [&](int e, f4a p[4], float4& wv) {
            const int ec = (cn > 0) ? ((e < cn) ? e : cn - 1) : 0;
            wv = (cn > 0) ? wtab[bsub][ec] : make_float4(0.f, 0.f, 0.f, 0.f);
            int ro = (cn > 0) ? ktab[bsub][ec] : 0;
            if (e >= cn) wv = make_float4(0.f, 0.f, 0.f, 0.f);  // pad: exact no-op
            const float* pb = Ct2 + ro + jq * 4;
            p[0] = *(const f4a*)(pb);
            p[1] = *(const f4a*)(pb + 64);
            p[2] = *(const f4a*)(pb + 128);
            p[3] = *(const f4a*)(pb + 192);
        };
        f4a P0[4], P1[4]; float4 W0, W1;
        ldb(0, P0, W0);
        ldb(1, P1, W1);
        for (int e = 0; e < cmax; ++e) {
            f4a P2[4]; float4 W2;
            ldb(e + 2, P2, W2);
            const double w0 = (double)W0.x, w1 = (double)W0.y;
            const double w2 = (double)W0.z, w3 = (double)W0.w;
            #pragma unroll
            for (int ee = 0; ee < 4; ++ee) {
                a3[ee] = fma(w0, (double)P0[0][ee], a3[ee]);   // k-asc == R6
                a3[ee] = fma(w1, (double)P0[1][ee], a3[ee]);
                a3[ee] = fma(w2, (double)P0[2][ee], a3[ee]);
                a3[ee] = fma(w3, (double)P0[3][ee], a3[ee]);
            }
            #pragma unroll
            for (int r = 0; r < 4; ++r) { P0[r] = P1[r]; P1[r] = P2[r]; }
            W0 = W1; W1 = W2;
        }
    }

    const float4 o = make_float4((float)a3[0], (float)a3[1],
                                 (float)a3[2], (float)a3[3]);
    *(float4*)(out + (size_t)(blockIdx.x * 4 + bsub) * 64 + jq * 4) = o;
}

// ---------------- fallback: R6 monolithic (zero workspace, proven) ----------

__device__ __forceinline__ void stage1(float xf, float sw[4], int& st) {
    const bool inr = (xf >= 0.0f) && (xf < 1.0f);
    if (!inr) { st = -1; sw[0] = sw[1] = sw[2] = sw[3] = 0.0f; return; }
    int t; float w[4];
    basis4(xf, t, w);
    sw[0] = w[0]; sw[1] = w[1]; sw[2] = w[2]; sw[3] = w[3];
    st = t;
}

template<int IN, int OUT>
__device__ __forceinline__ float gather_acc(const float* __restrict__ C, int j,
                                            const float (*__restrict__ sw)[4],
                                            const int* __restrict__ st) {
    double acc = 0.0;
    for (int i = 0; i < IN; ++i) {
        const int t = st[i];
        if (t < 0) continue;
        const float* Crow = C + ((size_t)i * OUT + j) * 64;
        #pragma unroll
        for (int r = 0; r < 4; ++r) {
            const int k4 = t - 3 + r;
            if (k4 >= 0 && k4 <= 63)
                acc += (double)sw[i][r] * (double)Crow[k4];
        }
    }
    return (float)acc;
}

__global__ __launch_bounds__(256) void kan_fused(const float* __restrict__ x,
                                                 const float* __restrict__ C0,
                                                 const float* __restrict__ C1,
                                                 const float* __restrict__ C2,
                                                 float* __restrict__ out) {
    __shared__ float cur[256];
    __shared__ float sw[256][4];
    __shared__ int   st[256];
    const int b = blockIdx.x, tid = threadIdx.x;

    if (tid < 64) stage1(x[(size_t)b * 64 + tid], sw[tid], st[tid]);
    __syncthreads();
    {
        const float a = gather_acc<64, 256>(C0, tid, sw, st);
        __syncthreads();
        cur[tid] = a;
    }
    __syncthreads();

    stage1(cur[tid], sw[tid], st[tid]);
    __syncthreads();
    {
        const float a = gather_acc<256, 256>(C1, tid, sw, st);
        __syncthreads();
        cur[tid] = a;
    }
    __syncthreads();

    stage1(cur[tid], sw[tid], st[tid]);
    __syncthreads();
    if (tid < 64) out[(size_t)b * 64 + tid] = gather_acc<256, 64>(C2, tid, sw, st);
}

// ---------------- launcher --------------------------------------------------

extern "C" void kernel_launch(void* const* d_in, const int* in_sizes, int n_in,
                              void* d_out, int out_size, void* d_ws, size_t ws_size,
                              hipStream_t stream) {
    const float* x  = (const float*)d_in[0];   // (4096, 64)
    const float* C0 = (const float*)d_in[1];   // (64, 256, 64)
    const float* C1 = (const float*)d_in[2];   // (256, 256, 64)
    const float* C2 = (const float*)d_in[3];   // (256, 64, 64)
    float* out = (float*)d_out;                // (4096, 64)

    const size_t CT1 = (size_t)256 * 64 * 256 * 4;   // 16.78 MB
    const size_t CT0 = (size_t)64  * 64 * 256 * 4;   //  4.19 MB
    const size_t CT2 = (size_t)256 * 64 * 64  * 4;   //  4.19 MB
    const size_t need = CT1 + CT0 + CT2;             // 25.17 MB (R14-R18 proven)

    if (ws_size >= need) {
        float* ct1 = (float*)d_ws;
        float* ct0 = (float*)((char*)d_ws + CT1);
        float* ct2 = (float*)((char*)d_ws + CT1 + CT0);

        transpose_fast<<<1536, 256, 0, stream>>>(C0, C1, C2, ct0, ct1, ct2);
        kan_mega3<<<1024, 256, 0, stream>>>(x, ct0, ct1, ct2, out);
    } else {
        kan_fused<<<NBATCH, 256, 0, stream>>>(x, C0, C1, C2, out);
    }
}